// Round 7
// baseline (193.877 us; speedup 1.0000x reference)
//
#include <hip/hip_runtime.h>

#define TT 200
#define BB 4096

typedef __bf16 bf16x8 __attribute__((ext_vector_type(8)));
typedef __bf16 bf16x4 __attribute__((ext_vector_type(4)));
typedef float  f32x4  __attribute__((ext_vector_type(4)));

#define L2E 1.4426950408889634f

__device__ __forceinline__ float fexp2(float x) { return __builtin_amdgcn_exp2f(x); }
__device__ __forceinline__ float frcp(float x)  { return __builtin_amdgcn_rcpf(x); }

// Fallback-path init: fill out[T*B] with fc_b[0].
__global__ void gru_init_out(float* __restrict__ out, const float* __restrict__ fc_b) {
    int i = blockIdx.x * blockDim.x + threadIdx.x;
    float v = fc_b[0];
    ((float4*)out)[i] = make_float4(v, v, v, v);
}

// combine: out = out(fwd partial) + ws(bwd partial) + fc_b
__global__ void gru_combine(float* __restrict__ out, const float* __restrict__ ws,
                            const float* __restrict__ fc_b) {
    int i = blockIdx.x * blockDim.x + threadIdx.x;
    float b = fc_b[0];
    float4 a = ((const float4*)out)[i];
    float4 w = ((const float4*)ws)[i];
    ((float4*)out)[i] = make_float4(a.x + w.x + b, a.y + w.y + b,
                                    a.z + w.z + b, a.w + w.w + b);
}

// Barrier-free MFMA GRU scan: ONE wave owns ONE 8-batch stream end-to-end
// (full 32-unit state). 1024 independent waves = 1 per SIMD; no cross-wave
// coupling -> the serial chain has no barrier/skew terms (the r6 stall).
// MFMA: A = weight tile [16 gate-rows x K=32 units], B = h [32 units x 16 cols]
// with batch cols 8-15 duplicating 0-7 (benign). 6 gate tiles: rows 16g..16g+15
// (r:0,1 z:2,3 n:4,5). r/z x-contribution folds into the h-MFMA via the C
// operand (accumulator chaining); n stays split (r multiplies only the h part).
// Lane (c0,q) gets gate rows 4q+i per tile -> r,z,n for units {4q+i, 16+4q+i},
// batch c0&7: 8 h-elements, 48 trans-class ops. h fp32 in regs; bf16 copy in
// LDS (single buffer; intra-wave DS ordering). Gate weights pre-scaled by
// -log2e (r,z) / 2log2e (n). fc partial: 32B coalesced plain store per step.
__global__ __launch_bounds__(64, 1) void gru_scan(
    const float* __restrict__ x,
    const float* __restrict__ w_ih_f, const float* __restrict__ w_hh_f,
    const float* __restrict__ b_ih_f, const float* __restrict__ b_hh_f,
    const float* __restrict__ w_ih_b, const float* __restrict__ w_hh_b,
    const float* __restrict__ b_ih_b, const float* __restrict__ b_hh_b,
    const float* __restrict__ fc_w,
    float* __restrict__ out_f, float* __restrict__ out_b,
    int atomic_mode)
{
    const int tile = blockIdx.x;          // 8-batch tile 0..511
    const int dir  = blockIdx.y;          // 0 fwd, 1 bwd
    const int lane = threadIdx.x;         // one wave per block
    const int c0   = lane & 15;           // B/D col (batch); A row (gate-row)
    const int q    = lane >> 4;           // k-chunk q*8..q*8+7; D rows 4q..4q+3
    const int bl   = c0 & 7;              // effective batch col (8-15 duplicate)
    const int b0   = tile * 8;

    const float* __restrict__ Wih = dir ? w_ih_b : w_ih_f;
    const float* __restrict__ Whh = dir ? w_hh_b : w_hh_f;
    const float* __restrict__ Bih = dir ? b_ih_b : b_ih_f;
    const float* __restrict__ Bhh = dir ? b_hh_b : b_hh_f;
    float* __restrict__ outp = dir ? out_b : out_f;

    // ---- static fragments ----
    // tile g: gate rows 16g+[0,16); lane's A row = 16g+c0; C rows = 16g+4q+i.
    // scale: r,z (g<4) -> -log2e ; n (g>=4) -> 2log2e.
    bf16x8 AW[6], AX[6], AFC;
    f32x4  CBrz[4];   // full bias (bih+bhh), goes into the r/z x-MFMA C
    f32x4  CBxn[2];   // bih only, n x-MFMA C
    f32x4  CBhn[2];   // bhh only, n h-MFMA C
    f32x4  CZ;
    CZ[0] = 0.f; CZ[1] = 0.f; CZ[2] = 0.f; CZ[3] = 0.f;
    #pragma unroll
    for (int g = 0; g < 6; ++g) {
        const float gsc = (g < 4) ? -L2E : 2.0f * L2E;
        const int arow = 16 * g + c0;
        const float* wrow = Whh + arow * 32 + q * 8;
        #pragma unroll
        for (int j = 0; j < 8; ++j) AW[g][j] = (__bf16)(gsc * wrow[j]);
        #pragma unroll
        for (int j = 0; j < 8; ++j)
            AX[g][j] = (q == 0 && j < 3) ? (__bf16)(gsc * Wih[arow * 3 + j]) : (__bf16)0.0f;
        #pragma unroll
        for (int i = 0; i < 4; ++i) {
            const int crow = 16 * g + 4 * q + i;
            if (g < 4)       CBrz[g][i]     = gsc * (Bih[crow] + Bhh[crow]);
            else           { CBxn[g - 4][i] = gsc * Bih[crow];
                             CBhn[g - 4][i] = gsc * Bhh[crow]; }
        }
    }
    // fc tile: A row 0 = fc_w over all 32 units
    #pragma unroll
    for (int j = 0; j < 8; ++j)
        AFC[j] = (c0 == 0) ? (__bf16)fc_w[dir * 32 + q * 8 + j] : (__bf16)0.0f;

    // ---- h state: fp32 in regs; bf16 copy in LDS [8 batch][40 units] ----
    float hA[4] = {0.f, 0.f, 0.f, 0.f};   // units 4q+i,    batch bl
    float hB[4] = {0.f, 0.f, 0.f, 0.f};   // units 16+4q+i, batch bl
    __shared__ __bf16 sh[8][40];
    if (c0 < 8) {
        bf16x4 zz; zz[0] = (__bf16)0.f; zz[1] = (__bf16)0.f; zz[2] = (__bf16)0.f; zz[3] = (__bf16)0.f;
        *(bf16x4*)&sh[c0][4 * q]      = zz;
        *(bf16x4*)&sh[c0][16 + 4 * q] = zz;
    }

    // x pointer-walk: lane loads x[t][b0+bl][0..2] (lanes 8-15 duplicate -> coalesce)
    const int  t_first = dir ? (TT - 1) : 0;
    const long xstep   = dir ? -(long)(BB * 3) : (long)(BB * 3);
    const long ostep   = dir ? -(long)BB : (long)BB;
    const float* xp = x + (size_t)t_first * (BB * 3) + (size_t)(b0 + bl) * 3;
    float* ocur = outp + (size_t)t_first * BB + b0;

    float xa = xp[0], xb = xp[1], xc = xp[2];

    for (int t = 0; t < TT; ++t) {
        // B fragment: full h state (one ds_read_b128; intra-wave ordered vs writes)
        bf16x8 Bh = *(const bf16x8*)&sh[bl][q * 8];

        // prefetch next x (no barriers anywhere -> stays in flight freely)
        const float* xpn = (t < TT - 1) ? (xp + xstep) : xp;
        float nxa = xpn[0], nxb = xpn[1], nxc = xpn[2];
        xp = xpn;

        // x B-fragment: rows k<3 only (AX zero elsewhere)
        bf16x8 Bx;
        Bx[0] = (__bf16)xa; Bx[1] = (__bf16)xb; Bx[2] = (__bf16)xc;
        Bx[3] = (__bf16)0.f; Bx[4] = (__bf16)0.f; Bx[5] = (__bf16)0.f;
        Bx[6] = (__bf16)0.f; Bx[7] = (__bf16)0.f;

        // r/z: x-MFMA (with full bias) chains into h-MFMA C operand
        f32x4 D[6];
        #pragma unroll
        for (int g = 0; g < 4; ++g) {
            f32x4 Dx = __builtin_amdgcn_mfma_f32_16x16x32_bf16(AX[g], Bx, CBrz[g], 0, 0, 0);
            D[g]     = __builtin_amdgcn_mfma_f32_16x16x32_bf16(AW[g], Bh, Dx,      0, 0, 0);
        }
        // n: keep x and h parts separate (r multiplies only the h part)
        f32x4 Dxn[2];
        #pragma unroll
        for (int g = 0; g < 2; ++g) {
            Dxn[g]   = __builtin_amdgcn_mfma_f32_16x16x32_bf16(AX[4 + g], Bx, CBxn[g], 0, 0, 0);
            D[4 + g] = __builtin_amdgcn_mfma_f32_16x16x32_bf16(AW[4 + g], Bh, CBhn[g], 0, 0, 0);
        }
        // fused FC on h_t -> out row t-1
        f32x4 Dfc = __builtin_amdgcn_mfma_f32_16x16x32_bf16(AFC, Bh, CZ, 0, 0, 0);
        if (t > 0 && q == 0 && c0 < 8) {
            float* oprev = ocur - ostep + c0;
            if (atomic_mode) atomicAdd(oprev, Dfc[0]);
            else             *oprev = Dfc[0];
        }

        // gates: sigmoid = rcp(1+exp2(s)); tanh = 1-2*rcp(1+exp2(y'))
        #pragma unroll
        for (int i = 0; i < 4; ++i) {
            float rA = frcp(1.0f + fexp2(D[0][i]));
            float rB = frcp(1.0f + fexp2(D[1][i]));
            float zA = frcp(1.0f + fexp2(D[2][i]));
            float zB = frcp(1.0f + fexp2(D[3][i]));
            float eA = fexp2(fmaf(rA, D[4][i], Dxn[0][i]));
            float eB = fexp2(fmaf(rB, D[5][i], Dxn[1][i]));
            float nA = fmaf(-2.0f, frcp(1.0f + eA), 1.0f);
            float nB = fmaf(-2.0f, frcp(1.0f + eB), 1.0f);
            hA[i] = fmaf(zA, hA[i] - nA, nA);
            hB[i] = fmaf(zB, hB[i] - nB, nB);
        }
        if (c0 < 8) {
            bf16x4 va, vb;
            #pragma unroll
            for (int i = 0; i < 4; ++i) { va[i] = (__bf16)hA[i]; vb[i] = (__bf16)hB[i]; }
            *(bf16x4*)&sh[c0][4 * q]      = va;   // ds_write_b64
            *(bf16x4*)&sh[c0][16 + 4 * q] = vb;
        }

        xa = nxa; xb = nxb; xc = nxc;
        ocur += ostep;
    }

    // epilogue: out row T-1 from the final state
    {
        bf16x8 Bh = *(const bf16x8*)&sh[bl][q * 8];
        f32x4 Dfc = __builtin_amdgcn_mfma_f32_16x16x32_bf16(AFC, Bh, CZ, 0, 0, 0);
        if (q == 0 && c0 < 8) {
            float* oprev = ocur - ostep + c0;
            if (atomic_mode) atomicAdd(oprev, Dfc[0]);
            else             *oprev = Dfc[0];
        }
    }
}

extern "C" void kernel_launch(void* const* d_in, const int* in_sizes, int n_in,
                              void* d_out, int out_size, void* d_ws, size_t ws_size,
                              hipStream_t stream) {
    const float* x      = (const float*)d_in[0];
    const float* w_ih_f = (const float*)d_in[1];
    const float* w_hh_f = (const float*)d_in[2];
    const float* b_ih_f = (const float*)d_in[3];
    const float* b_hh_f = (const float*)d_in[4];
    const float* w_ih_b = (const float*)d_in[5];
    const float* w_hh_b = (const float*)d_in[6];
    const float* b_ih_b = (const float*)d_in[7];
    const float* b_hh_b = (const float*)d_in[8];
    const float* fc_w   = (const float*)d_in[9];
    const float* fc_b   = (const float*)d_in[10];
    float* out = (float*)d_out;
    float* ws  = (float*)d_ws;

    const size_t need = (size_t)TT * BB * sizeof(float);
    dim3 grid(BB / 8, 2);   // 512 tiles x 2 dirs = 1024 single-wave blocks

    if (ws_size >= need) {
        // store path: fwd -> out, bwd -> ws, then combine (adds fc_b)
        gru_scan<<<grid, 64, 0, stream>>>(
            x, w_ih_f, w_hh_f, b_ih_f, b_hh_f,
            w_ih_b, w_hh_b, b_ih_b, b_hh_b, fc_w, out, ws, 0);
        gru_combine<<<(TT * BB / 4) / 256, 256, 0, stream>>>(out, ws, fc_b);
    } else {
        // atomic fallback: init out with fc_b, both dirs accumulate
        gru_init_out<<<(TT * BB / 4 + 255) / 256, 256, 0, stream>>>(out, fc_b);
        gru_scan<<<grid, 64, 0, stream>>>(
            x, w_ih_f, w_hh_f, b_ih_f, b_hh_f,
            w_ih_b, w_hh_b, b_ih_b, b_hh_b, fc_w, out, out, 1);
    }
}

// Round 8
// 182.189 us; speedup vs baseline: 1.0642x; 1.0642x over previous
//
#include <hip/hip_runtime.h>

#define TT 200
#define BB 4096

typedef __bf16 bf16x8 __attribute__((ext_vector_type(8)));
typedef float  f32x4  __attribute__((ext_vector_type(4)));

#define L2E 1.4426950408889634f

__device__ __forceinline__ float fexp2(float x) { return __builtin_amdgcn_exp2f(x); }
__device__ __forceinline__ float frcp(float x)  { return __builtin_amdgcn_rcpf(x); }

// Fallback-path init: fill out[T*B] with fc_b[0].
__global__ void gru_init_out(float* __restrict__ out, const float* __restrict__ fc_b) {
    int i = blockIdx.x * blockDim.x + threadIdx.x;
    float v = fc_b[0];
    ((float4*)out)[i] = make_float4(v, v, v, v);
}

// combine: out = out(fwd partial) + ws(bwd partial) + fc_b
__global__ void gru_combine(float* __restrict__ out, const float* __restrict__ ws,
                            const float* __restrict__ fc_b) {
    int i = blockIdx.x * blockDim.x + threadIdx.x;
    float b = fc_b[0];
    float4 a = ((const float4*)out)[i];
    float4 w = ((const float4*)ws)[i];
    ((float4*)out)[i] = make_float4(a.x + w.x + b, a.y + w.y + b,
                                    a.z + w.z + b, a.w + w.w + b);
}

// Fully register-resident MFMA GRU scan: one wave owns one 8-batch stream,
// h NEVER touches LDS. Trick: each gate is split into two 16-row A-tiles with
// PERMUTED rows -- sub-tile s row m carries weight row u = 8*(m>>2)+4s+(m&3),
// so lane (c0,q)'s D outputs are exactly units {8q+i} (s=0) and {8q+4+i} (s=1)
// for batch col c0 -- i.e. precisely the lane's next-step B fragment
// (B[k=8q+j][n=c0]). Chain per step: cvt -> MFMA -> gates -> cvt. No LDS, no
// barriers, no cross-lane. Batch cols 8-15 duplicate 0-7 (self-consistent).
// Gate weights pre-scaled by -log2e (r,z) / 2log2e (n); sigmoid/tanh =
// rcp(1+exp2(.)) off the MFMA result. fc partial: 32B coalesced plain store.
__global__ __launch_bounds__(64, 1) void gru_scan(
    const float* __restrict__ x,
    const float* __restrict__ w_ih_f, const float* __restrict__ w_hh_f,
    const float* __restrict__ b_ih_f, const float* __restrict__ b_hh_f,
    const float* __restrict__ w_ih_b, const float* __restrict__ w_hh_b,
    const float* __restrict__ b_ih_b, const float* __restrict__ b_hh_b,
    const float* __restrict__ fc_w,
    float* __restrict__ out_f, float* __restrict__ out_b,
    int atomic_mode)
{
    const int tile = blockIdx.x;          // 8-batch tile 0..511
    const int dir  = blockIdx.y;          // 0 fwd, 1 bwd
    const int lane = threadIdx.x;         // one wave per block
    const int c0   = lane & 15;           // B/D col (batch); A row index m
    const int q    = lane >> 4;           // k-chunk q*8..q*8+7; D rows 4q..4q+3
    const int bl   = c0 & 7;              // effective batch (cols 8-15 duplicate)
    const int b0   = tile * 8;

    const float* __restrict__ Wih = dir ? w_ih_b : w_ih_f;
    const float* __restrict__ Whh = dir ? w_hh_b : w_hh_f;
    const float* __restrict__ Bih = dir ? b_ih_b : b_ih_f;
    const float* __restrict__ Bhh = dir ? b_hh_b : b_hh_f;
    float* __restrict__ outp = dir ? out_b : out_f;

    // ---- static fragments, tile idx = 2*gate + s ----
    // A row m=c0 -> weight row 32*gate + 8*(c0>>2) + 4*s + (c0&3)
    // C row  m=4q+i -> weight row 32*gate + 8*q + 4*s + i
    bf16x8 AW[6], AX[6], AFC;
    f32x4  CBrz[4];   // r/z: full bias (bih+bhh) via the x-MFMA C operand
    f32x4  CBxn[2];   // n: bih via x-MFMA C
    f32x4  CBhn[2];   // n: bhh via h-MFMA C
    f32x4  CZ;
    CZ[0] = 0.f; CZ[1] = 0.f; CZ[2] = 0.f; CZ[3] = 0.f;
    #pragma unroll
    for (int gate = 0; gate < 3; ++gate) {
        const float gsc = (gate < 2) ? -L2E : 2.0f * L2E;
        #pragma unroll
        for (int s = 0; s < 2; ++s) {
            const int idx  = 2 * gate + s;
            const int arow = 32 * gate + 8 * (c0 >> 2) + 4 * s + (c0 & 3);
            const float* wrow = Whh + arow * 32 + q * 8;
            #pragma unroll
            for (int j = 0; j < 8; ++j) AW[idx][j] = (__bf16)(gsc * wrow[j]);
            #pragma unroll
            for (int j = 0; j < 8; ++j)
                AX[idx][j] = (q == 0 && j < 3) ? (__bf16)(gsc * Wih[arow * 3 + j])
                                               : (__bf16)0.0f;
            #pragma unroll
            for (int i = 0; i < 4; ++i) {
                const int crow = 32 * gate + 8 * q + 4 * s + i;
                if (gate < 2)  CBrz[idx][i] = gsc * (Bih[crow] + Bhh[crow]);
                else         { CBxn[s][i]   = gsc * Bih[crow];
                               CBhn[s][i]   = gsc * Bhh[crow]; }
            }
        }
    }
    // fc tile: A row 0 = fc_w over all 32 units (natural k order)
    #pragma unroll
    for (int j = 0; j < 8; ++j)
        AFC[j] = (c0 == 0) ? (__bf16)fc_w[dir * 32 + q * 8 + j] : (__bf16)0.0f;

    // ---- h state: fp32 regs; Bh = bf16 B-fragment rebuilt in regs each step ----
    float hA[4] = {0.f, 0.f, 0.f, 0.f};   // units 8q+i,   batch bl
    float hB[4] = {0.f, 0.f, 0.f, 0.f};   // units 8q+4+i, batch bl
    bf16x8 Bh;
    #pragma unroll
    for (int j = 0; j < 8; ++j) Bh[j] = (__bf16)0.0f;

    // x pointer-walk: lane loads x[t][b0+bl][0..2] (lanes 8-15 duplicate)
    const int  t_first = dir ? (TT - 1) : 0;
    const long xstep   = dir ? -(long)(BB * 3) : (long)(BB * 3);
    const long ostep   = dir ? -(long)BB : (long)BB;
    const float* xp = x + (size_t)t_first * (BB * 3) + (size_t)(b0 + bl) * 3;
    float* ocur = outp + (size_t)t_first * BB + b0;

    float xa = xp[0], xb = xp[1], xc = xp[2];

    for (int t = 0; t < TT; ++t) {
        // x B-fragment: rows k<3 only (AX zero elsewhere)
        bf16x8 Bx;
        Bx[0] = (__bf16)xa; Bx[1] = (__bf16)xb; Bx[2] = (__bf16)xc;
        Bx[3] = (__bf16)0.f; Bx[4] = (__bf16)0.f; Bx[5] = (__bf16)0.f;
        Bx[6] = (__bf16)0.f; Bx[7] = (__bf16)0.f;

        // prefetch next x (no barriers: stays in flight freely)
        const float* xpn = (t < TT - 1) ? (xp + xstep) : xp;
        float nxa = xpn[0], nxb = xpn[1], nxc = xpn[2];
        xp = xpn;

        // r/z: x-MFMA (with full bias in C) chains into h-MFMA C operand
        f32x4 D[6];
        #pragma unroll
        for (int g = 0; g < 4; ++g) {
            f32x4 Dx = __builtin_amdgcn_mfma_f32_16x16x32_bf16(AX[g], Bx, CBrz[g], 0, 0, 0);
            D[g]     = __builtin_amdgcn_mfma_f32_16x16x32_bf16(AW[g], Bh, Dx,      0, 0, 0);
        }
        // n: x and h parts separate (r multiplies only the h part)
        f32x4 Dxn[2];
        #pragma unroll
        for (int s = 0; s < 2; ++s) {
            Dxn[s]   = __builtin_amdgcn_mfma_f32_16x16x32_bf16(AX[4 + s], Bx, CBxn[s], 0, 0, 0);
            D[4 + s] = __builtin_amdgcn_mfma_f32_16x16x32_bf16(AW[4 + s], Bh, CBhn[s], 0, 0, 0);
        }
        // fused FC on h_{t-1} -> out row t-1
        f32x4 Dfc = __builtin_amdgcn_mfma_f32_16x16x32_bf16(AFC, Bh, CZ, 0, 0, 0);
        if (t > 0 && q == 0 && c0 < 8) {
            float* oprev = ocur - ostep + c0;
            if (atomic_mode) atomicAdd(oprev, Dfc[0]);
            else             *oprev = Dfc[0];
        }

        // gates: sigmoid = rcp(1+exp2(s)); tanh = 1-2*rcp(1+exp2(y'))
        #pragma unroll
        for (int i = 0; i < 4; ++i) {
            float rA = frcp(1.0f + fexp2(D[0][i]));
            float rB = frcp(1.0f + fexp2(D[1][i]));
            float zA = frcp(1.0f + fexp2(D[2][i]));
            float zB = frcp(1.0f + fexp2(D[3][i]));
            float eA = fexp2(fmaf(rA, D[4][i], Dxn[0][i]));
            float eB = fexp2(fmaf(rB, D[5][i], Dxn[1][i]));
            float nA = fmaf(-2.0f, frcp(1.0f + eA), 1.0f);
            float nB = fmaf(-2.0f, frcp(1.0f + eB), 1.0f);
            hA[i] = fmaf(zA, hA[i] - nA, nA);
            hB[i] = fmaf(zB, hB[i] - nB, nB);
        }
        // rebuild B fragment in regs: k=q*8+j -> j<4: unit 8q+j (hA), j>=4: hB
        #pragma unroll
        for (int i = 0; i < 4; ++i) {
            Bh[i]     = (__bf16)hA[i];
            Bh[4 + i] = (__bf16)hB[i];
        }

        xa = nxa; xb = nxb; xc = nxc;
        ocur += ostep;
    }

    // epilogue: out row T-1 from the final state
    {
        f32x4 Dfc = __builtin_amdgcn_mfma_f32_16x16x32_bf16(AFC, Bh, CZ, 0, 0, 0);
        if (q == 0 && c0 < 8) {
            float* oprev = ocur - ostep + c0;
            if (atomic_mode) atomicAdd(oprev, Dfc[0]);
            else             *oprev = Dfc[0];
        }
    }
}

extern "C" void kernel_launch(void* const* d_in, const int* in_sizes, int n_in,
                              void* d_out, int out_size, void* d_ws, size_t ws_size,
                              hipStream_t stream) {
    const float* x      = (const float*)d_in[0];
    const float* w_ih_f = (const float*)d_in[1];
    const float* w_hh_f = (const float*)d_in[2];
    const float* b_ih_f = (const float*)d_in[3];
    const float* b_hh_f = (const float*)d_in[4];
    const float* w_ih_b = (const float*)d_in[5];
    const float* w_hh_b = (const float*)d_in[6];
    const float* b_ih_b = (const float*)d_in[7];
    const float* b_hh_b = (const float*)d_in[8];
    const float* fc_w   = (const float*)d_in[9];
    const float* fc_b   = (const float*)d_in[10];
    float* out = (float*)d_out;
    float* ws  = (float*)d_ws;

    const size_t need = (size_t)TT * BB * sizeof(float);
    dim3 grid(BB / 8, 2);   // 512 tiles x 2 dirs = 1024 single-wave blocks

    if (ws_size >= need) {
        // store path: fwd -> out, bwd -> ws, then combine (adds fc_b)
        gru_scan<<<grid, 64, 0, stream>>>(
            x, w_ih_f, w_hh_f, b_ih_f, b_hh_f,
            w_ih_b, w_hh_b, b_ih_b, b_hh_b, fc_w, out, ws, 0);
        gru_combine<<<(TT * BB / 4) / 256, 256, 0, stream>>>(out, ws, fc_b);
    } else {
        // atomic fallback: init out with fc_b, both dirs accumulate
        gru_init_out<<<(TT * BB / 4 + 255) / 256, 256, 0, stream>>>(out, fc_b);
        gru_scan<<<grid, 64, 0, stream>>>(
            x, w_ih_f, w_hh_f, b_ih_f, b_hh_f,
            w_ih_b, w_hh_b, b_ih_b, b_hh_b, fc_w, out, out, 1);
    }
}